// Round 1
// baseline (1510.757 us; speedup 1.0000x reference)
//
#include <hip/hip_runtime.h>
#include <cmath>

#define HIDC 48

// ---------------------------------------------------------------------------
// block-wide mean/var over cnt values; each of 256 threads contributes s, s2.
// red must have >= 18 floats of shared storage.
// ---------------------------------------------------------------------------
__device__ __forceinline__ void block_meanvar(float s, float s2, float* red,
                                              float cntinv, float& m, float& v)
{
#pragma unroll
    for (int off = 32; off > 0; off >>= 1) {
        s  += __shfl_down(s, off);
        s2 += __shfl_down(s2, off);
    }
    int wid  = threadIdx.x >> 6;
    int lane = threadIdx.x & 63;
    if (lane == 0) { red[wid] = s; red[8 + wid] = s2; }
    __syncthreads();
    if (threadIdx.x == 0) {
        float ts = 0.f, ts2 = 0.f;
        for (int i = 0; i < 4; ++i) { ts += red[i]; ts2 += red[8 + i]; }
        red[16] = ts; red[17] = ts2;
    }
    __syncthreads();
    float mean = red[16] * cntinv;
    m = mean;
    v = red[17] * cntinv - mean * mean;
    __syncthreads();   // allow red reuse by a later reduction
}

// ---------------------------------------------------------------------------
// Fused conv3x3(SAME, zero-pad) + optional inorm/prelu/inorm/residual.
// One workgroup per (cout, n) plane, 256 threads.
// MODE 0: conv+bias, inorm, prelu(a), inorm, +residual   (basic_block)
// MODE 1: conv+bias, inorm, prelu(a)                     (prek head 1)
// MODE 2: conv+bias                                      (prek head 2)
// ---------------------------------------------------------------------------
template <int H, int W, int CIN, int MODE>
__global__ __launch_bounds__(256) void conv_block(
    const float* __restrict__ in,    // (N, CIN, H, W)
    const float* __restrict__ wgt,   // (COUT, CIN, 3, 3)
    const float* __restrict__ bias,  // (COUT)
    const float* __restrict__ aptr,  // prelu slope (scalar), may be null in MODE 2
    float* __restrict__ out)         // (N, COUT, H, W)
{
    constexpr int NPIX = H * W;
    constexpr int PPT  = NPIX / 256;
    __shared__ float plane[NPIX];
    __shared__ float red[18];

    const int t  = threadIdx.x;
    const int co = blockIdx.x;
    const int n  = blockIdx.y;

    float acc[PPT];
#pragma unroll
    for (int p = 0; p < PPT; ++p) acc[p] = 0.f;

    const float* wbase = wgt + (size_t)co * CIN * 9;
    const float* inb   = in + (size_t)n * CIN * NPIX;

    for (int ci = 0; ci < CIN; ++ci) {
        const float* ip = inb + (size_t)ci * NPIX;
#pragma unroll
        for (int p = 0; p < PPT; ++p) plane[t + p * 256] = ip[t + p * 256];
        float wk[9];
#pragma unroll
        for (int k = 0; k < 9; ++k) wk[k] = wbase[ci * 9 + k];
        __syncthreads();
#pragma unroll
        for (int p = 0; p < PPT; ++p) {
            int idx = t + p * 256;
            int y = idx / W, x = idx % W;
            float s = acc[p];
#pragma unroll
            for (int dy = 0; dy < 3; ++dy) {
                int yy = y + dy - 1;
                if (yy < 0 || yy >= H) continue;
#pragma unroll
                for (int dx = 0; dx < 3; ++dx) {
                    int xx = x + dx - 1;
                    if (xx < 0 || xx >= W) continue;
                    s += plane[yy * W + xx] * wk[dy * 3 + dx];
                }
            }
            acc[p] = s;
        }
        __syncthreads();
    }

    const float bv = bias[co];
#pragma unroll
    for (int p = 0; p < PPT; ++p) acc[p] += bv;

    const size_t obase = ((size_t)n * gridDim.x + co) * NPIX;

    if (MODE == 2) {
#pragma unroll
        for (int p = 0; p < PPT; ++p) out[obase + t + p * 256] = acc[p];
        return;
    }

    constexpr float cntinv = 1.f / (float)NPIX;

    // inorm 1
    {
        float s = 0.f, s2 = 0.f;
#pragma unroll
        for (int p = 0; p < PPT; ++p) { s += acc[p]; s2 += acc[p] * acc[p]; }
        float m, v;
        block_meanvar(s, s2, red, cntinv, m, v);
        float r = rsqrtf(v + 1e-5f);
#pragma unroll
        for (int p = 0; p < PPT; ++p) acc[p] = (acc[p] - m) * r;
    }

    // prelu
    {
        const float a = aptr[0];
#pragma unroll
        for (int p = 0; p < PPT; ++p) acc[p] = acc[p] >= 0.f ? acc[p] : a * acc[p];
    }

    if (MODE == 0) {
        // inorm 2
        float s = 0.f, s2 = 0.f;
#pragma unroll
        for (int p = 0; p < PPT; ++p) { s += acc[p]; s2 += acc[p] * acc[p]; }
        float m, v;
        block_meanvar(s, s2, red, cntinv, m, v);
        float r = rsqrtf(v + 1e-5f);
        const float* resp = inb + (size_t)co * NPIX;
#pragma unroll
        for (int p = 0; p < PPT; ++p)
            acc[p] = (acc[p] - m) * r + resp[t + p * 256];
    }

#pragma unroll
    for (int p = 0; p < PPT; ++p) out[obase + t + p * 256] = acc[p];
}

// ---------------------------------------------------------------------------
// x1 = x_[:, :, ::4, ::4]   (4,48,256,256) -> (4,48,64,64)
// ---------------------------------------------------------------------------
__global__ __launch_bounds__(256) void downsample4(const float* __restrict__ xin,
                                                   float* __restrict__ o)
{
    int idx = blockIdx.x * 256 + threadIdx.x;        // 4*48*64*64 = 786432
    int j = idx & 63;
    int i = (idx >> 6) & 63;
    int nc = idx >> 12;
    o[idx] = xin[((size_t)nc * 256 + i * 4) * 256 + j * 4];
}

// ---------------------------------------------------------------------------
// 2x2 max pool  (4,48,64,64) -> (4,48,32,32)
// ---------------------------------------------------------------------------
__global__ __launch_bounds__(256) void maxpool2k(const float* __restrict__ a,
                                                 float* __restrict__ o)
{
    int idx = blockIdx.x * 256 + threadIdx.x;        // 4*48*32*32 = 196608
    int j = idx & 31;
    int i = (idx >> 5) & 31;
    int nc = idx >> 10;
    const float* p = a + ((size_t)nc * 64 + i * 2) * 64 + j * 2;
    o[idx] = fmaxf(fmaxf(p[0], p[1]), fmaxf(p[64], p[65]));
}

// ---------------------------------------------------------------------------
// Fused: bilinear 8x upsample (align-corners style per reference) of skernel
// (4,9,32,32), per-pixel softmax over the 9 taps, and 3x3 reflect-padded
// apply to x (4,48,256,256). One block per (output row h, n); thread = w.
// ---------------------------------------------------------------------------
__global__ __launch_bounds__(256) void apply_fused(const float* __restrict__ x,
                                                   const float* __restrict__ sk,
                                                   float* __restrict__ out)
{
    __shared__ float skr[9][2][32];
    const int h = blockIdx.x;
    const int n = blockIdx.y;
    const int t = threadIdx.x;

    float fs = (float)h * 31.0f / 255.0f;
    int r0 = (int)fs;
    float fh = fs - (float)r0;
    int r1 = min(r0 + 1, 31);

    for (int i = t; i < 576; i += 256) {
        int p = i >> 6, rsel = (i >> 5) & 1, c = i & 31;
        int rr = rsel ? r1 : r0;
        skr[p][rsel][c] = sk[((n * 9 + p) * 32 + rr) * 32 + c];
    }
    __syncthreads();

    const int w = t;
    float fcs = (float)w * 31.0f / 255.0f;
    int c0 = (int)fcs;
    float fx = fcs - (float)c0;
    int c1 = min(c0 + 1, 31);

    float kv[9];
    float mx = -1e30f;
#pragma unroll
    for (int p = 0; p < 9; ++p) {
        float v0 = skr[p][0][c0] * (1.f - fx) + skr[p][0][c1] * fx;
        float v1 = skr[p][1][c0] * (1.f - fx) + skr[p][1][c1] * fx;
        float v  = v0 * (1.f - fh) + v1 * fh;
        kv[p] = v;
        mx = fmaxf(mx, v);
    }
    float ssum = 0.f;
#pragma unroll
    for (int p = 0; p < 9; ++p) { kv[p] = __expf(kv[p] - mx); ssum += kv[p]; }
    float inv = 1.f / ssum;
#pragma unroll
    for (int p = 0; p < 9; ++p) kv[p] *= inv;

    const int hm = (h == 0) ? 1 : h - 1;
    const int hp = (h == 255) ? 254 : h + 1;
    const int wm = (w == 0) ? 1 : w - 1;
    const int wp = (w == 255) ? 254 : w + 1;

    const float* xb = x + (size_t)n * HIDC * 65536;
    float* ob = out + (size_t)n * HIDC * 65536;
    for (int c = 0; c < HIDC; ++c) {
        const float* xp = xb + (size_t)c * 65536;
        float s = kv[0] * xp[hm * 256 + wm] + kv[1] * xp[hm * 256 + w] + kv[2] * xp[hm * 256 + wp]
                + kv[3] * xp[h  * 256 + wm] + kv[4] * xp[h  * 256 + w] + kv[5] * xp[h  * 256 + wp]
                + kv[6] * xp[hp * 256 + wm] + kv[7] * xp[hp * 256 + w] + kv[8] * xp[hp * 256 + wp];
        ob[(size_t)c * 65536 + h * 256 + w] = s;
    }
}

extern "C" void kernel_launch(void* const* d_in, const int* in_sizes, int n_in,
                              void* d_out, int out_size, void* d_ws, size_t ws_size,
                              hipStream_t stream)
{
    const float* x       = (const float*)d_in[0];
    const float* x_      = (const float*)d_in[1];
    const float* pre1_w  = (const float*)d_in[2];
    const float* pre1_b  = (const float*)d_in[3];
    const float* pre1_a  = (const float*)d_in[4];
    const float* pre2_w  = (const float*)d_in[5];
    const float* pre2_b  = (const float*)d_in[6];
    const float* pre2_a  = (const float*)d_in[7];
    const float* prek_w1 = (const float*)d_in[8];
    const float* prek_b1 = (const float*)d_in[9];
    const float* prek_a  = (const float*)d_in[10];
    const float* prek_w2 = (const float*)d_in[11];
    const float* prek_b2 = (const float*)d_in[12];
    float* out = (float*)d_out;

    float* A  = (float*)d_ws;                 // (4,48,64,64)
    float* B  = A + 4 * 48 * 64 * 64;         // (4,48,64,64)
    float* C  = B + 4 * 48 * 64 * 64;         // (4,48,32,32)
    float* D  = C + 4 * 48 * 32 * 32;         // (4,48,32,32)
    float* SK = D + 4 * 48 * 32 * 32;         // (4,9,32,32)

    const int W1 = 48 * 48 * 9;

    downsample4<<<3072, 256, 0, stream>>>(x_, A);

    conv_block<64, 64, 48, 0><<<dim3(48, 4), 256, 0, stream>>>(A, pre1_w,          pre1_b,      pre1_a,     B);
    conv_block<64, 64, 48, 0><<<dim3(48, 4), 256, 0, stream>>>(B, pre1_w + W1,     pre1_b + 48, pre1_a + 1, A);
    conv_block<64, 64, 48, 0><<<dim3(48, 4), 256, 0, stream>>>(A, pre1_w + 2 * W1, pre1_b + 96, pre1_a + 2, B);

    maxpool2k<<<768, 256, 0, stream>>>(B, C);

    conv_block<32, 32, 48, 0><<<dim3(48, 4), 256, 0, stream>>>(C, pre2_w,          pre2_b,      pre2_a,     D);
    conv_block<32, 32, 48, 0><<<dim3(48, 4), 256, 0, stream>>>(D, pre2_w + W1,     pre2_b + 48, pre2_a + 1, C);
    conv_block<32, 32, 48, 0><<<dim3(48, 4), 256, 0, stream>>>(C, pre2_w + 2 * W1, pre2_b + 96, pre2_a + 2, D);

    conv_block<32, 32, 48, 1><<<dim3(48, 4), 256, 0, stream>>>(D, prek_w1, prek_b1, prek_a, C);
    conv_block<32, 32, 48, 2><<<dim3(9, 4),  256, 0, stream>>>(C, prek_w2, prek_b2, nullptr, SK);

    apply_fused<<<dim3(256, 4), 256, 0, stream>>>(x, SK, out);
}

// Round 2
// 418.110 us; speedup vs baseline: 3.6133x; 3.6133x over previous
//
#include <hip/hip_runtime.h>
#include <cmath>

#define HIDC 48

// ---------------------------------------------------------------------------
// block-wide mean/var over NPIX values spread across 1024 threads.
// red must have >= 34 floats of shared storage.
// ---------------------------------------------------------------------------
__device__ __forceinline__ void block_meanvar1024(float s, float s2, float* red,
                                                  float cntinv, float& m, float& v)
{
#pragma unroll
    for (int off = 32; off > 0; off >>= 1) {
        s  += __shfl_down(s, off);
        s2 += __shfl_down(s2, off);
    }
    int wid  = threadIdx.x >> 6;   // 0..15
    int lane = threadIdx.x & 63;
    if (lane == 0) { red[wid] = s; red[16 + wid] = s2; }
    __syncthreads();
    if (threadIdx.x == 0) {
        float ts = 0.f, ts2 = 0.f;
#pragma unroll
        for (int i = 0; i < 16; ++i) { ts += red[i]; ts2 += red[16 + i]; }
        red[32] = ts; red[33] = ts2;
    }
    __syncthreads();
    float mean = red[32] * cntinv;
    m = mean;
    v = red[33] * cntinv - mean * mean;
    __syncthreads();   // allow red reuse by a later reduction
}

// ---------------------------------------------------------------------------
// Fused conv3x3(SAME, zero-pad) + optional inorm/prelu/inorm/residual.
// One workgroup of 1024 threads per (cout, n) plane.
//   MODE 0: conv+bias, inorm, prelu(a), inorm, +residual   (basic_block)
//   MODE 1: conv+bias, inorm, prelu(a)                     (prek head 1)
//   MODE 2: conv+bias                                      (prek head 2)
// Structure: CPS input channels staged per barrier into a zero-halo-padded
// double-buffered LDS plane; next stage's global loads prefetched into
// registers during compute; each thread owns a TY x 1 column strip of output
// pixels (TY = H*W/1024) -> 3*(TY+2) LDS reads per 3*TY*3 FMAs, all
// wave-stride-1 (conflict-free).
// ---------------------------------------------------------------------------
template <int H, int W, int CPS, int MODE>
__global__ __launch_bounds__(1024) void conv_block(
    const float* __restrict__ in,    // (N, 48, H, W)
    const float* __restrict__ wgt,   // (COUT, 48, 3, 3)
    const float* __restrict__ bias,  // (COUT)
    const float* __restrict__ aptr,  // prelu slope (scalar), null in MODE 2
    float* __restrict__ out)         // (N, COUT, H, W)
{
    constexpr int NPIX = H * W;
    constexpr int PW   = W + 2;
    constexpr int PSZ  = (H + 2) * PW;
    constexpr int TY   = NPIX / 1024;      // pixels per thread (column strip)
    constexpr int NS   = 48 / CPS;         // stages
    constexpr int LPT  = CPS * NPIX / 1024;// staged floats per thread per stage

    __shared__ float plane[2][CPS][PSZ];
    __shared__ float red[34];

    const int t  = threadIdx.x;
    const int co = blockIdx.x;
    const int n  = blockIdx.y;
    const int tx = t % W;
    const int ty = t / W;

    // zero both LDS buffers once (halo stays zero forever; interiors get
    // overwritten each stage). Covered by the stage-0 barrier.
    {
        float* lf = &plane[0][0][0];
        for (int i = t; i < 2 * CPS * PSZ; i += 1024) lf[i] = 0.f;
    }

    float acc[TY];
#pragma unroll
    for (int r = 0; r < TY; ++r) acc[r] = 0.f;

    const float* wbase = wgt + (size_t)co * 48 * 9;
    const float* inb   = in + (size_t)n * 48 * NPIX;

    float pref[LPT];
#pragma unroll
    for (int k = 0; k < LPT; ++k) pref[k] = inb[t + k * 1024];

    int buf = 0;
    for (int s = 0; s < NS; ++s) {
        float cur[LPT];
#pragma unroll
        for (int k = 0; k < LPT; ++k) cur[k] = pref[k];
        if (s + 1 < NS) {
            const float* nb = inb + (size_t)(s + 1) * CPS * NPIX;
#pragma unroll
            for (int k = 0; k < LPT; ++k) pref[k] = nb[t + k * 1024];
        }
        // stage cur into padded LDS interior
#pragma unroll
        for (int k = 0; k < LPT; ++k) {
            int fidx = t + k * 1024;
            int ch   = fidx / NPIX;
            int pix  = fidx % NPIX;
            int y    = pix / W, x = pix % W;
            plane[buf][ch][(y + 1) * PW + (x + 1)] = cur[k];
        }
        __syncthreads();

#pragma unroll
        for (int c = 0; c < CPS; ++c) {
            const float* wp = wbase + (size_t)(s * CPS + c) * 9;  // uniform
            float w0 = wp[0], w1 = wp[1], w2 = wp[2];
            float w3 = wp[3], w4 = wp[4], w5 = wp[5];
            float w6 = wp[6], w7 = wp[7], w8 = wp[8];
            const float* P = &plane[buf][c][0];
#pragma unroll
            for (int dx = 0; dx < 3; ++dx) {
                const int xcol = tx + dx;
                float v[TY + 2];
#pragma unroll
                for (int j = 0; j < TY + 2; ++j)
                    v[j] = P[(TY * ty + j) * PW + xcol];
                const float wa = (dx == 0) ? w0 : (dx == 1) ? w1 : w2;
                const float wb = (dx == 0) ? w3 : (dx == 1) ? w4 : w5;
                const float wc = (dx == 0) ? w6 : (dx == 1) ? w7 : w8;
#pragma unroll
                for (int r = 0; r < TY; ++r)
                    acc[r] += v[r] * wa + v[r + 1] * wb + v[r + 2] * wc;
            }
        }
        buf ^= 1;
        // no second barrier: next stage writes the other buffer, and every
        // thread finished reading buf^1 before it passed the barrier above.
        __syncthreads();
    }

    const float bv = bias[co];
#pragma unroll
    for (int r = 0; r < TY; ++r) acc[r] += bv;

    const size_t obase = ((size_t)n * gridDim.x + co) * NPIX;

    if (MODE == 2) {
#pragma unroll
        for (int r = 0; r < TY; ++r)
            out[obase + (TY * ty + r) * W + tx] = acc[r];
        return;
    }

    constexpr float cntinv = 1.f / (float)NPIX;

    // inorm 1
    {
        float s = 0.f, s2 = 0.f;
#pragma unroll
        for (int r = 0; r < TY; ++r) { s += acc[r]; s2 += acc[r] * acc[r]; }
        float m, v;
        block_meanvar1024(s, s2, red, cntinv, m, v);
        float rr = rsqrtf(v + 1e-5f);
#pragma unroll
        for (int r = 0; r < TY; ++r) acc[r] = (acc[r] - m) * rr;
    }

    // prelu
    {
        const float a = aptr[0];
#pragma unroll
        for (int r = 0; r < TY; ++r) acc[r] = acc[r] >= 0.f ? acc[r] : a * acc[r];
    }

    if (MODE == 0) {
        // inorm 2 + residual
        float s = 0.f, s2 = 0.f;
#pragma unroll
        for (int r = 0; r < TY; ++r) { s += acc[r]; s2 += acc[r] * acc[r]; }
        float m, v;
        block_meanvar1024(s, s2, red, cntinv, m, v);
        float rr = rsqrtf(v + 1e-5f);
        const float* resp = inb + (size_t)co * NPIX;
#pragma unroll
        for (int r = 0; r < TY; ++r)
            acc[r] = (acc[r] - m) * rr + resp[(TY * ty + r) * W + tx];
    }

#pragma unroll
    for (int r = 0; r < TY; ++r)
        out[obase + (TY * ty + r) * W + tx] = acc[r];
}

// ---------------------------------------------------------------------------
// x1 = x_[:, :, ::4, ::4]   (4,48,256,256) -> (4,48,64,64)
// ---------------------------------------------------------------------------
__global__ __launch_bounds__(256) void downsample4(const float* __restrict__ xin,
                                                   float* __restrict__ o)
{
    int idx = blockIdx.x * 256 + threadIdx.x;        // 4*48*64*64 = 786432
    int j = idx & 63;
    int i = (idx >> 6) & 63;
    int nc = idx >> 12;
    o[idx] = xin[((size_t)nc * 256 + i * 4) * 256 + j * 4];
}

// ---------------------------------------------------------------------------
// 2x2 max pool  (4,48,64,64) -> (4,48,32,32)
// ---------------------------------------------------------------------------
__global__ __launch_bounds__(256) void maxpool2k(const float* __restrict__ a,
                                                 float* __restrict__ o)
{
    int idx = blockIdx.x * 256 + threadIdx.x;        // 4*48*32*32 = 196608
    int j = idx & 31;
    int i = (idx >> 5) & 31;
    int nc = idx >> 10;
    const float* p = a + ((size_t)nc * 64 + i * 2) * 64 + j * 2;
    o[idx] = fmaxf(fmaxf(p[0], p[1]), fmaxf(p[64], p[65]));
}

// ---------------------------------------------------------------------------
// Fused: bilinear 8x upsample of skernel (4,9,32,32), per-pixel softmax over
// the 9 taps, and 3x3 reflect-padded apply to x (4,48,256,256).
// One block per (output row h, n); thread = w.
// ---------------------------------------------------------------------------
__global__ __launch_bounds__(256) void apply_fused(const float* __restrict__ x,
                                                   const float* __restrict__ sk,
                                                   float* __restrict__ out)
{
    __shared__ float skr[9][2][32];
    const int h = blockIdx.x;
    const int n = blockIdx.y;
    const int t = threadIdx.x;

    float fs = (float)h * 31.0f / 255.0f;
    int r0 = (int)fs;
    float fh = fs - (float)r0;
    int r1 = min(r0 + 1, 31);

    for (int i = t; i < 576; i += 256) {
        int p = i >> 6, rsel = (i >> 5) & 1, c = i & 31;
        int rr = rsel ? r1 : r0;
        skr[p][rsel][c] = sk[((n * 9 + p) * 32 + rr) * 32 + c];
    }
    __syncthreads();

    const int w = t;
    float fcs = (float)w * 31.0f / 255.0f;
    int c0 = (int)fcs;
    float fx = fcs - (float)c0;
    int c1 = min(c0 + 1, 31);

    float kv[9];
    float mx = -1e30f;
#pragma unroll
    for (int p = 0; p < 9; ++p) {
        float v0 = skr[p][0][c0] * (1.f - fx) + skr[p][0][c1] * fx;
        float v1 = skr[p][1][c0] * (1.f - fx) + skr[p][1][c1] * fx;
        float v  = v0 * (1.f - fh) + v1 * fh;
        kv[p] = v;
        mx = fmaxf(mx, v);
    }
    float ssum = 0.f;
#pragma unroll
    for (int p = 0; p < 9; ++p) { kv[p] = __expf(kv[p] - mx); ssum += kv[p]; }
    float inv = 1.f / ssum;
#pragma unroll
    for (int p = 0; p < 9; ++p) kv[p] *= inv;

    const int hm = (h == 0) ? 1 : h - 1;
    const int hp = (h == 255) ? 254 : h + 1;
    const int wm = (w == 0) ? 1 : w - 1;
    const int wp = (w == 255) ? 254 : w + 1;

    const float* xb = x + (size_t)n * HIDC * 65536;
    float* ob = out + (size_t)n * HIDC * 65536;
    for (int c = 0; c < HIDC; ++c) {
        const float* xp = xb + (size_t)c * 65536;
        float s = kv[0] * xp[hm * 256 + wm] + kv[1] * xp[hm * 256 + w] + kv[2] * xp[hm * 256 + wp]
                + kv[3] * xp[h  * 256 + wm] + kv[4] * xp[h  * 256 + w] + kv[5] * xp[h  * 256 + wp]
                + kv[6] * xp[hp * 256 + wm] + kv[7] * xp[hp * 256 + w] + kv[8] * xp[hp * 256 + wp];
        ob[(size_t)c * 65536 + h * 256 + w] = s;
    }
}

extern "C" void kernel_launch(void* const* d_in, const int* in_sizes, int n_in,
                              void* d_out, int out_size, void* d_ws, size_t ws_size,
                              hipStream_t stream)
{
    const float* x       = (const float*)d_in[0];
    const float* x_      = (const float*)d_in[1];
    const float* pre1_w  = (const float*)d_in[2];
    const float* pre1_b  = (const float*)d_in[3];
    const float* pre1_a  = (const float*)d_in[4];
    const float* pre2_w  = (const float*)d_in[5];
    const float* pre2_b  = (const float*)d_in[6];
    const float* pre2_a  = (const float*)d_in[7];
    const float* prek_w1 = (const float*)d_in[8];
    const float* prek_b1 = (const float*)d_in[9];
    const float* prek_a  = (const float*)d_in[10];
    const float* prek_w2 = (const float*)d_in[11];
    const float* prek_b2 = (const float*)d_in[12];
    float* out = (float*)d_out;

    float* A  = (float*)d_ws;                 // (4,48,64,64)
    float* B  = A + 4 * 48 * 64 * 64;         // (4,48,64,64)
    float* C  = B + 4 * 48 * 64 * 64;         // (4,48,32,32)
    float* D  = C + 4 * 48 * 32 * 32;         // (4,48,32,32)
    float* SK = D + 4 * 48 * 32 * 32;         // (4,9,32,32)

    const int W1 = 48 * 48 * 9;

    downsample4<<<3072, 256, 0, stream>>>(x_, A);

    conv_block<64, 64, 2, 0><<<dim3(48, 4), 1024, 0, stream>>>(A, pre1_w,          pre1_b,      pre1_a,     B);
    conv_block<64, 64, 2, 0><<<dim3(48, 4), 1024, 0, stream>>>(B, pre1_w + W1,     pre1_b + 48, pre1_a + 1, A);
    conv_block<64, 64, 2, 0><<<dim3(48, 4), 1024, 0, stream>>>(A, pre1_w + 2 * W1, pre1_b + 96, pre1_a + 2, B);

    maxpool2k<<<768, 256, 0, stream>>>(B, C);

    conv_block<32, 32, 4, 0><<<dim3(48, 4), 1024, 0, stream>>>(C, pre2_w,          pre2_b,      pre2_a,     D);
    conv_block<32, 32, 4, 0><<<dim3(48, 4), 1024, 0, stream>>>(D, pre2_w + W1,     pre2_b + 48, pre2_a + 1, C);
    conv_block<32, 32, 4, 0><<<dim3(48, 4), 1024, 0, stream>>>(C, pre2_w + 2 * W1, pre2_b + 96, pre2_a + 2, D);

    conv_block<32, 32, 4, 1><<<dim3(48, 4), 1024, 0, stream>>>(D, prek_w1, prek_b1, prek_a, C);
    conv_block<32, 32, 4, 2><<<dim3(9, 4),  1024, 0, stream>>>(C, prek_w2, prek_b2, nullptr, SK);

    apply_fused<<<dim3(256, 4), 256, 0, stream>>>(x, SK, out);
}

// Round 3
// 397.027 us; speedup vs baseline: 3.8052x; 1.0531x over previous
//
#include <hip/hip_runtime.h>
#include <cmath>

#define HIDC 48

// ---------------------------------------------------------------------------
// block-wide mean/var over NPIX values spread across 1024 threads.
// red must have >= 34 floats of shared storage.
// ---------------------------------------------------------------------------
__device__ __forceinline__ void block_meanvar1024(float s, float s2, float* red,
                                                  float cntinv, float& m, float& v)
{
#pragma unroll
    for (int off = 32; off > 0; off >>= 1) {
        s  += __shfl_down(s, off);
        s2 += __shfl_down(s2, off);
    }
    int wid  = threadIdx.x >> 6;   // 0..15
    int lane = threadIdx.x & 63;
    if (lane == 0) { red[wid] = s; red[16 + wid] = s2; }
    __syncthreads();
    if (threadIdx.x == 0) {
        float ts = 0.f, ts2 = 0.f;
#pragma unroll
        for (int i = 0; i < 16; ++i) { ts += red[i]; ts2 += red[16 + i]; }
        red[32] = ts; red[33] = ts2;
    }
    __syncthreads();
    float mean = red[32] * cntinv;
    m = mean;
    v = red[33] * cntinv - mean * mean;
    __syncthreads();   // allow red reuse by a later reduction
}

// ---------------------------------------------------------------------------
// Fused conv3x3(SAME, zero-pad) + optional inorm/prelu/inorm/residual.
// One workgroup of 1024 threads per (cout, n) plane.
//   MODE 0: conv+bias, inorm, prelu(a), inorm, +residual   (basic_block)
//   MODE 1: conv+bias, inorm, prelu(a)                     (prek head 1)
//   MODE 2: conv+bias                                      (prek head 2)
// DS: input is read with spatial stride DS (fuses the ::4,::4 downsample).
// One barrier per stage (double-buffered LDS makes the 2nd barrier
// unnecessary: stage s+1 writes the buffer last read at s-1, and every
// thread's s-1 compute precedes its stage-s barrier in program order).
// ---------------------------------------------------------------------------
template <int H, int W, int CPS, int MODE, int DS>
__global__ __launch_bounds__(1024) void conv_block(
    const float* __restrict__ in,    // (N, 48, H*DS, W*DS)
    const float* __restrict__ wgt,   // (COUT, 48, 3, 3)
    const float* __restrict__ bias,  // (COUT)
    const float* __restrict__ aptr,  // prelu slope (scalar), null in MODE 2
    float* __restrict__ out)         // (N, COUT, H, W)
{
    constexpr int NPIX = H * W;
    constexpr int PW   = W + 2;
    constexpr int PSZ  = (H + 2) * PW;
    constexpr int TY   = NPIX / 1024;       // pixels per thread (column strip)
    constexpr int NS   = 48 / CPS;          // stages
    constexpr int LPT  = CPS * NPIX / 1024; // staged floats per thread per stage
    constexpr int INROW = W * DS;
    constexpr size_t CSTRIDE = (size_t)NPIX * DS * DS;

    __shared__ float plane[2][CPS][PSZ];
    __shared__ float red[34];

    const int t  = threadIdx.x;
    const int co = blockIdx.x;
    const int n  = blockIdx.y;
    const int tx = t % W;
    const int ty = t / W;

    // zero both LDS buffers once (halo stays zero forever).
    {
        float* lf = &plane[0][0][0];
        for (int i = t; i < 2 * CPS * PSZ; i += 1024) lf[i] = 0.f;
    }

    float acc[TY];
#pragma unroll
    for (int r = 0; r < TY; ++r) acc[r] = 0.f;

    const float* wbase = wgt + (size_t)co * 48 * 9;
    const float* inb   = in + (size_t)n * 48 * CSTRIDE;

    float pref[LPT];
#pragma unroll
    for (int k = 0; k < LPT; ++k) {
        int fidx = t + k * 1024;
        int ch = fidx / NPIX, pix = fidx % NPIX, y = pix / W, x = pix % W;
        pref[k] = inb[(size_t)ch * CSTRIDE + (size_t)(y * DS) * INROW + x * DS];
    }

    int buf = 0;
    for (int s = 0; s < NS; ++s) {
        float cur[LPT];
#pragma unroll
        for (int k = 0; k < LPT; ++k) cur[k] = pref[k];
        if (s + 1 < NS) {
            const float* nb = inb + (size_t)(s + 1) * CPS * CSTRIDE;
#pragma unroll
            for (int k = 0; k < LPT; ++k) {
                int fidx = t + k * 1024;
                int ch = fidx / NPIX, pix = fidx % NPIX, y = pix / W, x = pix % W;
                pref[k] = nb[(size_t)ch * CSTRIDE + (size_t)(y * DS) * INROW + x * DS];
            }
        }
        // stage cur into padded LDS interior
#pragma unroll
        for (int k = 0; k < LPT; ++k) {
            int fidx = t + k * 1024;
            int ch   = fidx / NPIX;
            int pix  = fidx % NPIX;
            int y    = pix / W, x = pix % W;
            plane[buf][ch][(y + 1) * PW + (x + 1)] = cur[k];
        }
        __syncthreads();

#pragma unroll
        for (int c = 0; c < CPS; ++c) {
            const float* wp = wbase + (size_t)(s * CPS + c) * 9;  // uniform
            float w0 = wp[0], w1 = wp[1], w2 = wp[2];
            float w3 = wp[3], w4 = wp[4], w5 = wp[5];
            float w6 = wp[6], w7 = wp[7], w8 = wp[8];
            const float* P = &plane[buf][c][0];
#pragma unroll
            for (int dx = 0; dx < 3; ++dx) {
                const int xcol = tx + dx;
                float v[TY + 2];
#pragma unroll
                for (int j = 0; j < TY + 2; ++j)
                    v[j] = P[(TY * ty + j) * PW + xcol];
                const float wa = (dx == 0) ? w0 : (dx == 1) ? w1 : w2;
                const float wb = (dx == 0) ? w3 : (dx == 1) ? w4 : w5;
                const float wc = (dx == 0) ? w6 : (dx == 1) ? w7 : w8;
#pragma unroll
                for (int r = 0; r < TY; ++r)
                    acc[r] += v[r] * wa + v[r + 1] * wb + v[r + 2] * wc;
            }
        }
        buf ^= 1;
    }

    const float bv = bias[co];
#pragma unroll
    for (int r = 0; r < TY; ++r) acc[r] += bv;

    const size_t obase = ((size_t)n * gridDim.x + co) * NPIX;

    if (MODE == 2) {
#pragma unroll
        for (int r = 0; r < TY; ++r)
            out[obase + (TY * ty + r) * W + tx] = acc[r];
        return;
    }

    constexpr float cntinv = 1.f / (float)NPIX;

    // inorm 1
    {
        float s = 0.f, s2 = 0.f;
#pragma unroll
        for (int r = 0; r < TY; ++r) { s += acc[r]; s2 += acc[r] * acc[r]; }
        float m, v;
        block_meanvar1024(s, s2, red, cntinv, m, v);
        float rr = rsqrtf(v + 1e-5f);
#pragma unroll
        for (int r = 0; r < TY; ++r) acc[r] = (acc[r] - m) * rr;
    }

    // prelu
    {
        const float a = aptr[0];
#pragma unroll
        for (int r = 0; r < TY; ++r) acc[r] = acc[r] >= 0.f ? acc[r] : a * acc[r];
    }

    if (MODE == 0) {
        // inorm 2 + residual (residual read honors DS stride)
        float s = 0.f, s2 = 0.f;
#pragma unroll
        for (int r = 0; r < TY; ++r) { s += acc[r]; s2 += acc[r] * acc[r]; }
        float m, v;
        block_meanvar1024(s, s2, red, cntinv, m, v);
        float rr = rsqrtf(v + 1e-5f);
        const float* resp = inb + (size_t)co * CSTRIDE;
#pragma unroll
        for (int r = 0; r < TY; ++r)
            acc[r] = (acc[r] - m) * rr +
                     resp[(size_t)((TY * ty + r) * DS) * INROW + tx * DS];
    }

#pragma unroll
    for (int r = 0; r < TY; ++r)
        out[obase + (TY * ty + r) * W + tx] = acc[r];
}

// ---------------------------------------------------------------------------
// 2x2 max pool  (4,48,64,64) -> (4,48,32,32)
// ---------------------------------------------------------------------------
__global__ __launch_bounds__(256) void maxpool2k(const float* __restrict__ a,
                                                 float* __restrict__ o)
{
    int idx = blockIdx.x * 256 + threadIdx.x;        // 4*48*32*32 = 196608
    int j = idx & 31;
    int i = (idx >> 5) & 31;
    int nc = idx >> 10;
    const float* p = a + ((size_t)nc * 64 + i * 2) * 64 + j * 2;
    o[idx] = fmaxf(fmaxf(p[0], p[1]), fmaxf(p[64], p[65]));
}

// ---------------------------------------------------------------------------
// Fused: bilinear 8x upsample of skernel (4,9,32,32), per-pixel softmax over
// the 9 taps, and 3x3 reflect-padded apply to x (4,48,256,256).
// Grid (16, 256): x = n*4+cgroup (12 channels each), y = output row h.
// Phase 1: 256 threads compute softmaxed kv[9] for the whole row into LDS.
// Phase 2: thread t -> pixel quad w4=(t&63)*4, channels cg*12+(t>>6)*3+{0,1,2};
//          3 rows x (float4 + 2 edge scalars) per channel, float4 store.
// ---------------------------------------------------------------------------
__global__ __launch_bounds__(256) void apply_fused(const float* __restrict__ x,
                                                   const float* __restrict__ sk,
                                                   float* __restrict__ out)
{
    __shared__ float skr[9][2][32];
    __shared__ float kvs[256 * 9];   // [w][9]
    const int bx = blockIdx.x;
    const int n  = bx >> 2;
    const int cg = bx & 3;
    const int h  = blockIdx.y;
    const int t  = threadIdx.x;

    float fs = (float)h * 31.0f / 255.0f;
    int r0 = (int)fs;
    float fh = fs - (float)r0;
    int r1 = min(r0 + 1, 31);

    for (int i = t; i < 576; i += 256) {
        int p = i >> 6, rsel = (i >> 5) & 1, c = i & 31;
        int rr = rsel ? r1 : r0;
        skr[p][rsel][c] = sk[((n * 9 + p) * 32 + rr) * 32 + c];
    }
    __syncthreads();

    // phase 1: kv for pixel w = t
    {
        float fcs = (float)t * 31.0f / 255.0f;
        int c0 = (int)fcs;
        float fx = fcs - (float)c0;
        int c1 = min(c0 + 1, 31);
        float kv[9];
        float mx = -1e30f;
#pragma unroll
        for (int p = 0; p < 9; ++p) {
            float v0 = skr[p][0][c0] * (1.f - fx) + skr[p][0][c1] * fx;
            float v1 = skr[p][1][c0] * (1.f - fx) + skr[p][1][c1] * fx;
            float v  = v0 * (1.f - fh) + v1 * fh;
            kv[p] = v;
            mx = fmaxf(mx, v);
        }
        float ss = 0.f;
#pragma unroll
        for (int p = 0; p < 9; ++p) { kv[p] = __expf(kv[p] - mx); ss += kv[p]; }
        float inv = 1.f / ss;
#pragma unroll
        for (int p = 0; p < 9; ++p) kvs[t * 9 + p] = kv[p] * inv;
    }
    __syncthreads();

    const int wq = t & 63;
    const int cl = t >> 6;
    const int w4 = wq * 4;

    float kv[4][9];
#pragma unroll
    for (int j = 0; j < 4; ++j)
#pragma unroll
        for (int p = 0; p < 9; ++p) kv[j][p] = kvs[(w4 + j) * 9 + p];

    const int hm  = (h == 0) ? 1 : h - 1;
    const int hp  = (h == 255) ? 254 : h + 1;
    const int xle = (w4 == 0) ? 1 : w4 - 1;
    const int xre = (w4 == 252) ? 254 : w4 + 4;

    const int c0ch = cg * 12 + cl * 3;
    const float* xb = x + ((size_t)n * HIDC + c0ch) * 65536;
    float* ob = out + ((size_t)n * HIDC + c0ch) * 65536;

    for (int c = 0; c < 3; ++c) {
        const float* xp = xb + (size_t)c * 65536;
        const float* rm = xp + hm * 256;
        const float* rc = xp + h * 256;
        const float* rp = xp + hp * 256;
        float4 fm = *(const float4*)(rm + w4);
        float4 fc = *(const float4*)(rc + w4);
        float4 fp = *(const float4*)(rp + w4);
        float vm[6] = { rm[xle], fm.x, fm.y, fm.z, fm.w, rm[xre] };
        float vc[6] = { rc[xle], fc.x, fc.y, fc.z, fc.w, rc[xre] };
        float vp[6] = { rp[xle], fp.x, fp.y, fp.z, fp.w, rp[xre] };
        float4 o;
        float* op = &o.x;
#pragma unroll
        for (int j = 0; j < 4; ++j) {
            op[j] = kv[j][0] * vm[j] + kv[j][1] * vm[j + 1] + kv[j][2] * vm[j + 2]
                  + kv[j][3] * vc[j] + kv[j][4] * vc[j + 1] + kv[j][5] * vc[j + 2]
                  + kv[j][6] * vp[j] + kv[j][7] * vp[j + 1] + kv[j][8] * vp[j + 2];
        }
        *(float4*)(ob + (size_t)c * 65536 + h * 256 + w4) = o;
    }
}

extern "C" void kernel_launch(void* const* d_in, const int* in_sizes, int n_in,
                              void* d_out, int out_size, void* d_ws, size_t ws_size,
                              hipStream_t stream)
{
    const float* x       = (const float*)d_in[0];
    const float* x_      = (const float*)d_in[1];
    const float* pre1_w  = (const float*)d_in[2];
    const float* pre1_b  = (const float*)d_in[3];
    const float* pre1_a  = (const float*)d_in[4];
    const float* pre2_w  = (const float*)d_in[5];
    const float* pre2_b  = (const float*)d_in[6];
    const float* pre2_a  = (const float*)d_in[7];
    const float* prek_w1 = (const float*)d_in[8];
    const float* prek_b1 = (const float*)d_in[9];
    const float* prek_a  = (const float*)d_in[10];
    const float* prek_w2 = (const float*)d_in[11];
    const float* prek_b2 = (const float*)d_in[12];
    float* out = (float*)d_out;

    float* A  = (float*)d_ws;                 // (4,48,64,64)
    float* B  = A + 4 * 48 * 64 * 64;         // (4,48,64,64)
    float* C  = B + 4 * 48 * 64 * 64;         // (4,48,32,32)
    float* D  = C + 4 * 48 * 32 * 32;         // (4,48,32,32)
    float* SK = D + 4 * 48 * 32 * 32;         // (4,9,32,32)

    const int W1 = 48 * 48 * 9;

    // block 1 reads x_ directly with stride-4 staging (fused downsample)
    conv_block<64, 64, 4, 0, 4><<<dim3(48, 4), 1024, 0, stream>>>(x_, pre1_w,          pre1_b,      pre1_a,     B);
    conv_block<64, 64, 4, 0, 1><<<dim3(48, 4), 1024, 0, stream>>>(B,  pre1_w + W1,     pre1_b + 48, pre1_a + 1, A);
    conv_block<64, 64, 4, 0, 1><<<dim3(48, 4), 1024, 0, stream>>>(A,  pre1_w + 2 * W1, pre1_b + 96, pre1_a + 2, B);

    maxpool2k<<<768, 256, 0, stream>>>(B, C);

    conv_block<32, 32, 8, 0, 1><<<dim3(48, 4), 1024, 0, stream>>>(C, pre2_w,          pre2_b,      pre2_a,     D);
    conv_block<32, 32, 8, 0, 1><<<dim3(48, 4), 1024, 0, stream>>>(D, pre2_w + W1,     pre2_b + 48, pre2_a + 1, C);
    conv_block<32, 32, 8, 0, 1><<<dim3(48, 4), 1024, 0, stream>>>(C, pre2_w + 2 * W1, pre2_b + 96, pre2_a + 2, D);

    conv_block<32, 32, 8, 1, 1><<<dim3(48, 4), 1024, 0, stream>>>(D, prek_w1, prek_b1, prek_a, C);
    conv_block<32, 32, 8, 2, 1><<<dim3(9, 4),  1024, 0, stream>>>(C, prek_w2, prek_b2, nullptr, SK);

    apply_fused<<<dim3(16, 256), 256, 0, stream>>>(x, SK, out);
}